// Round 9
// baseline (71.718 us; speedup 1.0000x reference)
//
#include <hip/hip_runtime.h>
#include <float.h>

#define NB    16
#define CIN   64
#define NPT   16384
#define NRING 16
#define MAXR  1520
#define LTOT  (NRING*MAXR)   // 24320
#define MBLK  380            // LTOT/64
#define NCH   128
#define MW    380

typedef float fx4 __attribute__((ext_vector_type(4)));

__device__ __forceinline__ float sload(float v) {
    // force a wave-uniform value into an SGPR
    return __int_as_float(__builtin_amdgcn_readfirstlane(__float_as_int(v)));
}

#if __has_builtin(__builtin_amdgcn_global_load_lds)
#define HAVE_GLDS 1
__device__ __forceinline__ void gl_lds16(const float* g, float* l) {
    __builtin_amdgcn_global_load_lds(
        (const __attribute__((address_space(1))) void*)g,
        (__attribute__((address_space(3))) void*)l, 16, 0, 0);
}
#else
#define HAVE_GLDS 0
#endif

// K1 (persistent, double-buffered): 512 blocks, each owns (b, h) and processes
// 4 consecutive cp tiles. Wave w = ring g8 (weights wave-uniform -> SGPR).
// Lane: r = lane>>2 (output ring), s = lane&3 (m-split; trip count 5 or 6).
// LDS: xs[2][8192] x double-buffer (64 KB) + iw fused index words (12 KB,
// staged ONCE: choice tails depend on (b,ring), not cp). 76 KB -> 2 blocks/CU.
// Pipeline: issue global_load_lds for tile t+1, compute tile t, one barrier.
// iw[m] = cg[760+m] | cg[1140+m]<<16 covers all 4 conv rows (c0/c1 identity).
// Sign-fold: gamma<0 channels use negated weights/bias; only max tracked.
__global__ __launch_bounds__(512) void k1_gather_conv(
    const float* __restrict__ x, const float* __restrict__ Wg,
    const float* __restrict__ bias, const float* __restrict__ gamma,
    const int* __restrict__ choice,
    float* __restrict__ p_sum, float* __restrict__ p_sqs,
    float* __restrict__ p_max)
{
    __shared__ float xs[2][8192];    // 64 KB double buffer
    __shared__ int   iw[8*MW];       // 12160 B

    const int bid  = blockIdx.x;
    const int bh    = bid >> 4;      // 32 (b,h) combos
    const int slice = bid & 15;
    const int b  = bh >> 1;
    const int h  = bh & 1;
    const int cp0 = slice << 2;      // 4 tiles: cp0..cp0+3
    const int t    = threadIdx.x;
    const int w    = t >> 6;         // wave id = local ring g8
    const int lane = t & 63;

#if HAVE_GLDS
    #define STAGE(bufi, cpv) do { \
        const float* gb_ = x + ((size_t)(b*CIN + (cpv)))*NPT + h*8192 + w*1024 + lane*4; \
        float* lb_ = &xs[bufi][w*1024]; \
        gl_lds16(gb_,       lb_);       \
        gl_lds16(gb_ + 256, lb_ + 256); \
        gl_lds16(gb_ + 512, lb_ + 512); \
        gl_lds16(gb_ + 768, lb_ + 768); \
    } while (0)
#else
    #define STAGE(bufi, cpv) do { \
        const fx4* src_ = (const fx4*)(x + ((size_t)(b*CIN + (cpv)))*NPT + h*8192); \
        fx4* dst_ = (fx4*)xs[bufi]; \
        _Pragma("unroll") \
        for (int i_ = 0; i_ < 4; ++i_) dst_[t + i_*512] = src_[t + i_*512]; \
    } while (0)
#endif

    // issue first tile's x stage, then overlap: index staging + weight setup
    STAGE(0, cp0);

    {   // wave w builds ring w's fused index words (coalesced L2/L3 reads)
        const int* __restrict__ cg = choice + ((size_t)(b*NRING + h*8 + w))*MAXR;
        #pragma unroll
        for (int k = 0; k < 6; ++k) {
            const int m = lane + k*64;
            if (m < MW) iw[w*MW + m] = cg[760 + m] | (cg[1140 + m] << 16);
        }
    }

    const int g = h*8 + w;
    float wq[8][4], bq[8], sg8[8];
    #pragma unroll
    for (int o = 0; o < 8; ++o) {
        const int ch = g*8 + o;
        const float sgn = (gamma[ch] < 0.0f) ? -1.0f : 1.0f;
        sg8[o] = sload(sgn);
        bq[o]  = sload(sgn * bias[ch]);
        #pragma unroll
        for (int c = 0; c < 4; ++c) wq[o][c] = sload(sgn * Wg[ch*4 + c]);
    }

    const int r = lane >> 2;
    const int s = lane & 3;
    const int* __restrict__ igw = iw + w*MW;

    __syncthreads();   // drains stage (vmcnt) + iw writes (lgkm), then barrier

    for (int tt = 0; tt < 4; ++tt) {
        const int cp = cp0 + tt;
        const float* __restrict__ xg = &xs[tt & 1][w << 10];
        if (tt < 3) STAGE((tt + 1) & 1, cp + 1);   // prefetch next tile

        const int mlo = (r*MAXR - cp + 63) >> 6;
        int mhi = ((r+1)*MAXR - cp + 63) >> 6;
        if (mhi > MBLK) mhi = MBLK;
        const int m0 = mlo + s;

        int wv[5];
        #pragma unroll
        for (int k = 0; k < 5; ++k) wv[k] = igw[m0 + 4*k];

        float smax[8], ssum[8], ssq[8];
        #pragma unroll
        for (int o = 0; o < 8; ++o) { smax[o] = -FLT_MAX; ssum[o] = 0.f; ssq[o] = 0.f; }

        #pragma unroll
        for (int k = 0; k < 5; ++k) {
            const int m = m0 + 4*k;
            const int i2 = wv[k] & 0xFFFF;
            const int i3 = ((unsigned)wv[k]) >> 16;
            const float v0 = xg[m];
            const float v1 = xg[380 + m];
            const float v2 = xg[i2];
            const float v3 = xg[i3];
            #pragma unroll
            for (int o = 0; o < 8; ++o) {
                float y = fmaf(wq[o][0], v0, fmaf(wq[o][1], v1,
                          fmaf(wq[o][2], v2, fmaf(wq[o][3], v3, bq[o]))));
                smax[o] = fmaxf(smax[o], y);
                ssum[o] += y;
                ssq[o]  = fmaf(y, y, ssq[o]);
            }
        }
        {   // guarded 6th iteration
            const int m = m0 + 20;
            if (m < mhi) {
                const int wt = igw[m];
                const int i2 = wt & 0xFFFF;
                const int i3 = ((unsigned)wt) >> 16;
                const float v0 = xg[m];
                const float v1 = xg[380 + m];
                const float v2 = xg[i2];
                const float v3 = xg[i3];
                #pragma unroll
                for (int o = 0; o < 8; ++o) {
                    float y = fmaf(wq[o][0], v0, fmaf(wq[o][1], v1,
                              fmaf(wq[o][2], v2, fmaf(wq[o][3], v3, bq[o]))));
                    smax[o] = fmaxf(smax[o], y);
                    ssum[o] += y;
                    ssq[o]  = fmaf(y, y, ssq[o]);
                }
            }
        }

        // combine the four s-copies (lanes xor 1, xor 2) — deterministic
        #pragma unroll
        for (int o = 0; o < 8; ++o) {
            smax[o] = fmaxf(smax[o], __shfl_xor(smax[o], 1));
            ssum[o] += __shfl_xor(ssum[o], 1);
            ssq[o]  += __shfl_xor(ssq[o], 1);
            smax[o] = fmaxf(smax[o], __shfl_xor(smax[o], 2));
            ssum[o] += __shfl_xor(ssum[o], 2);
            ssq[o]  += __shfl_xor(ssq[o], 2);
        }

        // ring-max partials [b*64+cp][r][128ch]; this wave owns ch = h*64 + w*8 + o
        if (s == 0) {
            float* base = p_max + (((size_t)(b*64 + cp))*NRING + r)*NCH + h*64 + w*8;
            ((float4*)base)[0] = make_float4(smax[0], smax[1], smax[2], smax[3]);
            ((float4*)base)[1] = make_float4(smax[4], smax[5], smax[6], smax[7]);
        }

        // full-wave butterfly for channel sums (replaces LDS scratch + barrier)
        #pragma unroll
        for (int o = 0; o < 8; ++o) {
            #pragma unroll
            for (int off = 4; off < 64; off <<= 1) {
                ssum[o] += __shfl_xor(ssum[o], off);
                ssq[o]  += __shfl_xor(ssq[o], off);
            }
        }
        if (lane == 0) {
            float* baseS = p_sum + ((size_t)((b*64 + cp)*2 + h))*64 + w*8;
            float* baseQ = p_sqs + ((size_t)((b*64 + cp)*2 + h))*64 + w*8;
            ((float4*)baseS)[0] = make_float4(sg8[0]*ssum[0], sg8[1]*ssum[1], sg8[2]*ssum[2], sg8[3]*ssum[3]);
            ((float4*)baseS)[1] = make_float4(sg8[4]*ssum[4], sg8[5]*ssum[5], sg8[6]*ssum[6], sg8[7]*ssum[7]);
            ((float4*)baseQ)[0] = make_float4(ssq[0], ssq[1], ssq[2], ssq[3]);
            ((float4*)baseQ)[1] = make_float4(ssq[4], ssq[5], ssq[6], ssq[7]);
        }

        __syncthreads();   // waves done reading buf; next stage completed (vmcnt drain)
    }
    #undef STAGE
}

// K23: fused {channel stats + pool-reduce + BN affine + broadcast write}.
// block = (b, ch). Stats recomputed redundantly per block (8KB L2 reads).
__global__ __launch_bounds__(256) void k23_pool_bcast(
    const float* __restrict__ p_sum, const float* __restrict__ p_sqs,
    const float* __restrict__ p_max,
    const float* __restrict__ gamma, const float* __restrict__ beta,
    fx4* __restrict__ out)
{
    __shared__ float part[16][17];
    __shared__ float wsum[4], wsq[4];
    __shared__ float pool[16];
    const int bc = blockIdx.x;           // b*128 + ch
    const int b  = bc >> 7;
    const int ch = bc & 127;
    const int t  = threadIdx.x;
    const int hh = ch >> 6, c64 = ch & 63;

    // p_max slice reduce (sign-folded maxima)
    const int r = t >> 4, ck = t & 15;
    float v = -FLT_MAX;
    #pragma unroll
    for (int k = 0; k < 4; ++k) {
        const int cpi = ck*4 + k;
        v = fmaxf(v, p_max[(((size_t)(b*64 + cpi))*NRING + r)*NCH + ch]);
    }

    // channel stats: sum this channel's 1024 (b,cp) partials
    float S = 0.f, Q = 0.f;
    #pragma unroll
    for (int i = 0; i < 4; ++i) {
        const int jj = t + i*256;        // [0,1024)
        const int b2 = jj >> 6, cp2 = jj & 63;
        const int kb = b2*128 + cp2*2 + hh;
        S += p_sum[(size_t)kb*64 + c64];
        Q += p_sqs[(size_t)kb*64 + c64];
    }
    #pragma unroll
    for (int off = 1; off < 64; off <<= 1) {
        S += __shfl_xor(S, off);
        Q += __shfl_xor(Q, off);
    }
    part[r][ck] = v;
    if ((t & 63) == 0) { wsum[t >> 6] = S; wsq[t >> 6] = Q; }
    __syncthreads();

    if (t < 16) {
        const float inv = 1.0f / (float)((size_t)NB * LTOT);
        const float Sa = wsum[0] + wsum[1] + wsum[2] + wsum[3];
        const float Qa = wsq[0] + wsq[1] + wsq[2] + wsq[3];
        const float mean = Sa * inv;
        const float var  = Qa * inv - mean*mean;
        const float istd = rsqrtf(var + 1e-5f);
        float acc = part[t][0];
        #pragma unroll
        for (int k = 1; k < 16; ++k) acc = fmaxf(acc, part[t][k]);
        const float gm = gamma[ch];
        const float raw = (gm >= 0.0f) ? acc : -acc;   // un-fold sign
        pool[t] = gm * (raw - mean) * istd + beta[ch];
    }
    __syncthreads();

    fx4* __restrict__ dst = out + (size_t)bc * (NPT/4);
    #pragma unroll
    for (int i = 0; i < 16; ++i) {
        const int idx = t + i*256;            // [0,4096)
        const float vv = pool[idx >> 8];
        fx4 val; val.x = vv; val.y = vv; val.z = vv; val.w = vv;
        __builtin_nontemporal_store(val, &dst[idx]);
    }
}

extern "C" void kernel_launch(void* const* d_in, const int* in_sizes, int n_in,
                              void* d_out, int out_size, void* d_ws, size_t ws_size,
                              hipStream_t stream)
{
    const float* x     = (const float*)d_in[0];
    const float* Wg    = (const float*)d_in[1];
    const float* bias  = (const float*)d_in[2];
    const float* gamma = (const float*)d_in[3];
    const float* beta  = (const float*)d_in[4];
    const int* choice  = (const int*)d_in[6];

    float* p_sum = (float*)d_ws;                           // 2048*64
    float* p_sqs = p_sum + (size_t)2048*64;                // 2048*64
    float* p_max = p_sqs + (size_t)2048*64;                // 1024*16*128

    k1_gather_conv<<<512, 512, 0, stream>>>(x, Wg, bias, gamma, choice,
                                            p_sum, p_sqs, p_max);
    k23_pool_bcast<<<NB*NCH, 256, 0, stream>>>(p_sum, p_sqs, p_max,
                                               gamma, beta, (fx4*)d_out);
}

// Round 10
// 68.726 us; speedup vs baseline: 1.0435x; 1.0435x over previous
//
#include <hip/hip_runtime.h>
#include <float.h>

#define NB    16
#define CIN   64
#define NPT   16384
#define NRING 16
#define MAXR  1520
#define LTOT  (NRING*MAXR)   // 24320
#define MBLK  380            // LTOT/64
#define NCH   128

typedef float fx4 __attribute__((ext_vector_type(4)));

__device__ __forceinline__ float sload(float v) {
    // force a wave-uniform value into an SGPR
    return __int_as_float(__builtin_amdgcn_readfirstlane(__float_as_int(v)));
}

__device__ __forceinline__ void gl_lds16(const float* g, float* l) {
    __builtin_amdgcn_global_load_lds(
        (const __attribute__((address_space(1))) void*)g,
        (__attribute__((address_space(3))) void*)l, 16, 0, 0);
}

// K1 (barrier-free): block = (b, cp, q); wave w owns ring g = q*4+w EXCLUSIVELY.
// Every resource is wave-private, so there is NO __syncthreads at all:
//  (1) 4x global_load_lds stage ring g's 4KB of x[b][cp] into xs[w] (linear dest),
//  (2) coalesced int4 loads of choice tail -> pack iw[m]=c2|c3<<16 -> ds_write iw[w]
//      (same-wave DS ordering, compiler-managed lgkmcnt),
//  (3) one explicit s_waitcnt vmcnt(0), then pure LDS+VALU compute.
// Waves free-run; stage latency of one wave hides under compute of others.
// Lane: r = lane>>2 (output ring), s = lane&3 (m-split, trip 5 + guarded 6th).
// choice[p]=p for p<1024 makes c=0,1 rows identity (no index); c=2,c=3 use iw.
// Sign-fold: gamma<0 channels use negated weights/bias; only max tracked.
__global__ __launch_bounds__(256) void k1_gather_conv(
    const float* __restrict__ x, const float* __restrict__ Wg,
    const float* __restrict__ bias, const float* __restrict__ gamma,
    const int* __restrict__ choice,
    float* __restrict__ p_sum, float* __restrict__ p_sqs,
    float* __restrict__ p_max)
{
    __shared__ float xs[4][1024];    // 16 KB, wave-private 4KB regions
    __shared__ int   iw[4][384];     // 6 KB, wave-private fused index words

    const int blk = blockIdx.x;
    const int b  = blk >> 8;
    const int cp = (blk >> 2) & 63;
    const int q  = blk & 3;
    const int t  = threadIdx.x;
    const int w  = t >> 6;           // wave id
    const int lane = t & 63;
    const int g  = q*4 + w;          // global ring/group index

    // (1) direct-to-LDS stage of ring g (wave-uniform LDS base, lane*16B global)
    {
        const float* gb = x + ((size_t)(b*CIN + cp))*NPT + (g << 10) + lane*4;
        float* lb = &xs[w][0];
        gl_lds16(gb,       lb);
        gl_lds16(gb + 256, lb + 256);
        gl_lds16(gb + 512, lb + 512);
        gl_lds16(gb + 768, lb + 768);
    }

    // (2) wave-private fused index words (coalesced int4 global loads)
    {
        const int* __restrict__ cg = choice + ((size_t)(b*NRING + g))*MAXR;
        #pragma unroll
        for (int k = 0; k < 2; ++k) {
            const int j = lane + k*64;       // int4 slot in [0,95)
            if (j < 95) {
                const int4 a = *(const int4*)(cg + 760  + 4*j);
                const int4 c = *(const int4*)(cg + 1140 + 4*j);
                int4 p;
                p.x = a.x | (c.x << 16); p.y = a.y | (c.y << 16);
                p.z = a.z | (c.z << 16); p.w = a.w | (c.w << 16);
                *(int4*)(&iw[w][4*j]) = p;
            }
        }
    }

    // wave-uniform weights/bias (sign-folded) -> SGPRs; loads overlap the stage
    float wq[8][4], bq[8], sg8[8];
    #pragma unroll
    for (int o = 0; o < 8; ++o) {
        const int ch = g*8 + o;
        const float sgn = (gamma[ch] < 0.0f) ? -1.0f : 1.0f;
        sg8[o] = sload(sgn);
        bq[o]  = sload(sgn * bias[ch]);
        #pragma unroll
        for (int c = 0; c < 4; ++c) wq[o][c] = sload(sgn * Wg[ch*4 + c]);
    }

    const int r = lane >> 2;
    const int s = lane & 3;
    const int mlo = (r*MAXR - cp + 63) >> 6;
    int mhi = ((r+1)*MAXR - cp + 63) >> 6;
    if (mhi > MBLK) mhi = MBLK;
    const int m0 = mlo + s;

    // drain the global_load_lds fill before any xs read (compiler can't see dep)
    asm volatile("s_waitcnt vmcnt(0)" ::: "memory");

    const float* __restrict__ xg  = &xs[w][0];
    const int*   __restrict__ igw = &iw[w][0];

    int wv[5];
    #pragma unroll
    for (int k = 0; k < 5; ++k) wv[k] = igw[m0 + 4*k];

    float smax[8], ssum[8], ssq[8];
    #pragma unroll
    for (int o = 0; o < 8; ++o) { smax[o] = -FLT_MAX; ssum[o] = 0.f; ssq[o] = 0.f; }

    #pragma unroll
    for (int k = 0; k < 5; ++k) {
        const int m  = m0 + 4*k;
        const int i2 = wv[k] & 0xFFFF;
        const int i3 = ((unsigned)wv[k]) >> 16;
        const float v0 = xg[m];           // c=0: identity
        const float v1 = xg[380 + m];     // c=1: identity
        const float v2 = xg[i2];          // c=2
        const float v3 = xg[i3];          // c=3
        #pragma unroll
        for (int o = 0; o < 8; ++o) {
            float y = fmaf(wq[o][0], v0, fmaf(wq[o][1], v1,
                      fmaf(wq[o][2], v2, fmaf(wq[o][3], v3, bq[o]))));
            smax[o] = fmaxf(smax[o], y);
            ssum[o] += y;
            ssq[o]  = fmaf(y, y, ssq[o]);
        }
    }
    {   // guarded 6th iteration
        const int m = m0 + 20;
        if (m < mhi) {
            const int wt = igw[m];
            const int i2 = wt & 0xFFFF;
            const int i3 = ((unsigned)wt) >> 16;
            const float v0 = xg[m];
            const float v1 = xg[380 + m];
            const float v2 = xg[i2];
            const float v3 = xg[i3];
            #pragma unroll
            for (int o = 0; o < 8; ++o) {
                float y = fmaf(wq[o][0], v0, fmaf(wq[o][1], v1,
                          fmaf(wq[o][2], v2, fmaf(wq[o][3], v3, bq[o]))));
                smax[o] = fmaxf(smax[o], y);
                ssum[o] += y;
                ssq[o]  = fmaf(y, y, ssq[o]);
            }
        }
    }

    // combine the four s-copies (lanes xor 1, xor 2) — deterministic
    #pragma unroll
    for (int o = 0; o < 8; ++o) {
        smax[o] = fmaxf(smax[o], __shfl_xor(smax[o], 1));
        ssum[o] += __shfl_xor(ssum[o], 1);
        ssq[o]  += __shfl_xor(ssq[o], 1);
        smax[o] = fmaxf(smax[o], __shfl_xor(smax[o], 2));
        ssum[o] += __shfl_xor(ssum[o], 2);
        ssq[o]  += __shfl_xor(ssq[o], 2);
    }

    // ring-max partials [b*64+cp][r][128ch]; this wave owns ch = g*8 .. g*8+7
    if (s == 0) {
        float* base = p_max + (((size_t)(b*64 + cp))*NRING + r)*NCH + g*8;
        ((float4*)base)[0] = make_float4(smax[0], smax[1], smax[2], smax[3]);
        ((float4*)base)[1] = make_float4(smax[4], smax[5], smax[6], smax[7]);
    }

    // full-wave butterfly for channel sums (wave-internal, no LDS, no barrier)
    #pragma unroll
    for (int o = 0; o < 8; ++o) {
        #pragma unroll
        for (int off = 4; off < 64; off <<= 1) {
            ssum[o] += __shfl_xor(ssum[o], off);
            ssq[o]  += __shfl_xor(ssq[o], off);
        }
    }
    if (lane == 0) {
        float* baseS = p_sum + ((size_t)(b*64 + cp))*NCH + g*8;
        float* baseQ = p_sqs + ((size_t)(b*64 + cp))*NCH + g*8;
        ((float4*)baseS)[0] = make_float4(sg8[0]*ssum[0], sg8[1]*ssum[1], sg8[2]*ssum[2], sg8[3]*ssum[3]);
        ((float4*)baseS)[1] = make_float4(sg8[4]*ssum[4], sg8[5]*ssum[5], sg8[6]*ssum[6], sg8[7]*ssum[7]);
        ((float4*)baseQ)[0] = make_float4(ssq[0], ssq[1], ssq[2], ssq[3]);
        ((float4*)baseQ)[1] = make_float4(ssq[4], ssq[5], ssq[6], ssq[7]);
    }
}

// K23: fused {channel stats + pool-reduce + BN affine + broadcast write}.
// block = (b, ch). Stats recomputed redundantly per block (8KB L2 reads).
__global__ __launch_bounds__(256) void k23_pool_bcast(
    const float* __restrict__ p_sum, const float* __restrict__ p_sqs,
    const float* __restrict__ p_max,
    const float* __restrict__ gamma, const float* __restrict__ beta,
    fx4* __restrict__ out)
{
    __shared__ float part[16][17];
    __shared__ float wsum[4], wsq[4];
    __shared__ float pool[16];
    const int bc = blockIdx.x;           // b*128 + ch
    const int b  = bc >> 7;
    const int ch = bc & 127;
    const int t  = threadIdx.x;

    // p_max slice reduce (sign-folded maxima)
    const int r = t >> 4, ck = t & 15;
    float v = -FLT_MAX;
    #pragma unroll
    for (int k = 0; k < 4; ++k) {
        const int cpi = ck*4 + k;
        v = fmaxf(v, p_max[(((size_t)(b*64 + cpi))*NRING + r)*NCH + ch]);
    }

    // channel stats: sum this channel's 1024 (b,cp) partials
    float S = 0.f, Q = 0.f;
    #pragma unroll
    for (int i = 0; i < 4; ++i) {
        const int jj = t + i*256;        // [0,1024) = b2*64+cp2
        S += p_sum[(size_t)jj*NCH + ch];
        Q += p_sqs[(size_t)jj*NCH + ch];
    }
    #pragma unroll
    for (int off = 1; off < 64; off <<= 1) {
        S += __shfl_xor(S, off);
        Q += __shfl_xor(Q, off);
    }
    part[r][ck] = v;
    if ((t & 63) == 0) { wsum[t >> 6] = S; wsq[t >> 6] = Q; }
    __syncthreads();

    if (t < 16) {
        const float inv = 1.0f / (float)((size_t)NB * LTOT);
        const float Sa = wsum[0] + wsum[1] + wsum[2] + wsum[3];
        const float Qa = wsq[0] + wsq[1] + wsq[2] + wsq[3];
        const float mean = Sa * inv;
        const float var  = Qa * inv - mean*mean;
        const float istd = rsqrtf(var + 1e-5f);
        float acc = part[t][0];
        #pragma unroll
        for (int k = 1; k < 16; ++k) acc = fmaxf(acc, part[t][k]);
        const float gm = gamma[ch];
        const float raw = (gm >= 0.0f) ? acc : -acc;   // un-fold sign
        pool[t] = gm * (raw - mean) * istd + beta[ch];
    }
    __syncthreads();

    fx4* __restrict__ dst = out + (size_t)bc * (NPT/4);
    #pragma unroll
    for (int i = 0; i < 16; ++i) {
        const int idx = t + i*256;            // [0,4096)
        const float vv = pool[idx >> 8];
        fx4 val; val.x = vv; val.y = vv; val.z = vv; val.w = vv;
        __builtin_nontemporal_store(val, &dst[idx]);
    }
}

extern "C" void kernel_launch(void* const* d_in, const int* in_sizes, int n_in,
                              void* d_out, int out_size, void* d_ws, size_t ws_size,
                              hipStream_t stream)
{
    const float* x     = (const float*)d_in[0];
    const float* Wg    = (const float*)d_in[1];
    const float* bias  = (const float*)d_in[2];
    const float* gamma = (const float*)d_in[3];
    const float* beta  = (const float*)d_in[4];
    const int* choice  = (const int*)d_in[6];

    float* p_sum = (float*)d_ws;                           // 1024*128
    float* p_sqs = p_sum + (size_t)1024*NCH;               // 1024*128
    float* p_max = p_sqs + (size_t)1024*NCH;               // 1024*16*128

    k1_gather_conv<<<NB*CIN*4, 256, 0, stream>>>(x, Wg, bias, gamma, choice,
                                                 p_sum, p_sqs, p_max);
    k23_pool_bcast<<<NB*NCH, 256, 0, stream>>>(p_sum, p_sqs, p_max,
                                               gamma, beta, (fx4*)d_out);
}

// Round 11
// 62.300 us; speedup vs baseline: 1.1512x; 1.1031x over previous
//
#include <hip/hip_runtime.h>
#include <float.h>

#define NB    16
#define CIN   64
#define NPT   16384
#define NRING 16
#define MAXR  1520
#define LTOT  (NRING*MAXR)   // 24320
#define MBLK  380            // LTOT/64
#define NCH   128

typedef float fx4 __attribute__((ext_vector_type(4)));

__device__ __forceinline__ float sload(float v) {
    // force a wave-uniform value into an SGPR
    return __int_as_float(__builtin_amdgcn_readfirstlane(__float_as_int(v)));
}

// DPP move (VALU pipe, zero DS cost). CTRL: quad_perm / row_shr / row_bcast.
template<int CTRL>
__device__ __forceinline__ float fdpp(float v) {
    return __int_as_float(__builtin_amdgcn_mov_dpp(__float_as_int(v), CTRL, 0xF, 0xF, true));
}
#define DPP_QP_XOR1 0xB1   // quad_perm [1,0,3,2]
#define DPP_QP_XOR2 0x4E   // quad_perm [2,3,0,1]
#define DPP_SHR1  0x111
#define DPP_SHR2  0x112
#define DPP_SHR4  0x114
#define DPP_SHR8  0x118
#define DPP_BC15  0x142
#define DPP_BC31  0x143

__device__ __forceinline__ void gl_lds16(const float* g, float* l) {
    __builtin_amdgcn_global_load_lds(
        (const __attribute__((address_space(1))) void*)g,
        (__attribute__((address_space(3))) void*)l, 16, 0, 0);
}

// K1 (barrier-free, DPP reductions): block = (b, cp, q); wave w owns ring
// g = q*4+w exclusively; all LDS wave-private; zero __syncthreads.
//  (1) 4x global_load_lds stage ring g's 4KB of x[b][cp] into xs[w],
//  (2) coalesced int4 choice-tail loads -> pack iw[m]=c2|c3<<16 -> ds_write,
//  (3) s_waitcnt vmcnt(0), then pure LDS+VALU compute.
// Reductions: smax s-combine via quad_perm DPP (VALU); ssum/ssq via the
// classic 6-step DPP wave reduce (row_shr 1/2/4/8 + row_bcast 15/31), total
// in lane 63 -> direct pre-reduced [1024][128] store. NO shuffle DS ops.
// choice[p]=p for p<1024 => conv rows c=0,1 are identity (no index load).
// Sign-fold: gamma<0 channels use negated weights/bias; only max tracked.
__global__ __launch_bounds__(256) void k1_gather_conv(
    const float* __restrict__ x, const float* __restrict__ Wg,
    const float* __restrict__ bias, const float* __restrict__ gamma,
    const int* __restrict__ choice,
    float* __restrict__ p_sum, float* __restrict__ p_sqs,
    float* __restrict__ p_max)
{
    __shared__ float xs[4][1024];    // 16 KB, wave-private regions
    __shared__ int   iw[4][384];     // 6 KB, wave-private fused index words

    const int blk = blockIdx.x;
    const int b  = blk >> 8;
    const int cp = (blk >> 2) & 63;
    const int q  = blk & 3;
    const int t  = threadIdx.x;
    const int w  = t >> 6;           // wave id
    const int lane = t & 63;
    const int g  = q*4 + w;          // global ring/group index

    // (1) direct-to-LDS stage of ring g (wave-uniform LDS base, lane*16B)
    {
        const float* gb = x + ((size_t)(b*CIN + cp))*NPT + (g << 10) + lane*4;
        float* lb = &xs[w][0];
        gl_lds16(gb,       lb);
        gl_lds16(gb + 256, lb + 256);
        gl_lds16(gb + 512, lb + 512);
        gl_lds16(gb + 768, lb + 768);
    }

    // (2) wave-private fused index words (coalesced int4 global loads)
    {
        const int* __restrict__ cg = choice + ((size_t)(b*NRING + g))*MAXR;
        #pragma unroll
        for (int k = 0; k < 2; ++k) {
            const int j = lane + k*64;       // int4 slot in [0,95)
            if (j < 95) {
                const int4 a = *(const int4*)(cg + 760  + 4*j);
                const int4 c = *(const int4*)(cg + 1140 + 4*j);
                int4 p;
                p.x = a.x | (c.x << 16); p.y = a.y | (c.y << 16);
                p.z = a.z | (c.z << 16); p.w = a.w | (c.w << 16);
                *(int4*)(&iw[w][4*j]) = p;
            }
        }
    }

    // wave-uniform weights/bias (sign-folded) -> SGPRs; overlap the stage
    float wq[8][4], bq[8], sg8[8];
    #pragma unroll
    for (int o = 0; o < 8; ++o) {
        const int ch = g*8 + o;
        const float sgn = (gamma[ch] < 0.0f) ? -1.0f : 1.0f;
        sg8[o] = sload(sgn);
        bq[o]  = sload(sgn * bias[ch]);
        #pragma unroll
        for (int c = 0; c < 4; ++c) wq[o][c] = sload(sgn * Wg[ch*4 + c]);
    }

    const int r = lane >> 2;
    const int s = lane & 3;
    const int mlo = (r*MAXR - cp + 63) >> 6;
    int mhi = ((r+1)*MAXR - cp + 63) >> 6;
    if (mhi > MBLK) mhi = MBLK;
    const int m0 = mlo + s;

    // drain the global_load_lds fill before any xs read
    asm volatile("s_waitcnt vmcnt(0)" ::: "memory");

    const float* __restrict__ xg  = &xs[w][0];
    const int*   __restrict__ igw = &iw[w][0];

    int wv[5];
    #pragma unroll
    for (int k = 0; k < 5; ++k) wv[k] = igw[m0 + 4*k];

    float smax[8], ssum[8], ssq[8];
    #pragma unroll
    for (int o = 0; o < 8; ++o) { smax[o] = -FLT_MAX; ssum[o] = 0.f; ssq[o] = 0.f; }

    #pragma unroll
    for (int k = 0; k < 5; ++k) {
        const int m  = m0 + 4*k;
        const int i2 = wv[k] & 0xFFFF;
        const int i3 = ((unsigned)wv[k]) >> 16;
        const float v0 = xg[m];           // c=0: identity
        const float v1 = xg[380 + m];     // c=1: identity
        const float v2 = xg[i2];          // c=2
        const float v3 = xg[i3];          // c=3
        #pragma unroll
        for (int o = 0; o < 8; ++o) {
            float y = fmaf(wq[o][0], v0, fmaf(wq[o][1], v1,
                      fmaf(wq[o][2], v2, fmaf(wq[o][3], v3, bq[o]))));
            smax[o] = fmaxf(smax[o], y);
            ssum[o] += y;
            ssq[o]  = fmaf(y, y, ssq[o]);
        }
    }
    {   // guarded 6th iteration
        const int m = m0 + 20;
        if (m < mhi) {
            const int wt = igw[m];
            const int i2 = wt & 0xFFFF;
            const int i3 = ((unsigned)wt) >> 16;
            const float v0 = xg[m];
            const float v1 = xg[380 + m];
            const float v2 = xg[i2];
            const float v3 = xg[i3];
            #pragma unroll
            for (int o = 0; o < 8; ++o) {
                float y = fmaf(wq[o][0], v0, fmaf(wq[o][1], v1,
                          fmaf(wq[o][2], v2, fmaf(wq[o][3], v3, bq[o]))));
                smax[o] = fmaxf(smax[o], y);
                ssum[o] += y;
                ssq[o]  = fmaf(y, y, ssq[o]);
            }
        }
    }

    // smax: combine the 4 s-copies via quad_perm DPP (VALU-only)
    #pragma unroll
    for (int o = 0; o < 8; ++o) {
        smax[o] = fmaxf(smax[o], fdpp<DPP_QP_XOR1>(smax[o]));
        smax[o] = fmaxf(smax[o], fdpp<DPP_QP_XOR2>(smax[o]));
    }

    // ring-max partials [b*64+cp][r][128ch]; this wave owns ch = g*8 .. g*8+7
    if (s == 0) {
        float* base = p_max + (((size_t)(b*64 + cp))*NRING + r)*NCH + g*8;
        ((float4*)base)[0] = make_float4(smax[0], smax[1], smax[2], smax[3]);
        ((float4*)base)[1] = make_float4(smax[4], smax[5], smax[6], smax[7]);
    }

    // ssum/ssq: classic 6-step DPP wave reduce -> total in lane 63 (VALU-only)
    #pragma unroll
    for (int o = 0; o < 8; ++o) {
        ssum[o] += fdpp<DPP_SHR1>(ssum[o]);  ssq[o] += fdpp<DPP_SHR1>(ssq[o]);
        ssum[o] += fdpp<DPP_SHR2>(ssum[o]);  ssq[o] += fdpp<DPP_SHR2>(ssq[o]);
        ssum[o] += fdpp<DPP_SHR4>(ssum[o]);  ssq[o] += fdpp<DPP_SHR4>(ssq[o]);
        ssum[o] += fdpp<DPP_SHR8>(ssum[o]);  ssq[o] += fdpp<DPP_SHR8>(ssq[o]);
        ssum[o] += fdpp<DPP_BC15>(ssum[o]);  ssq[o] += fdpp<DPP_BC15>(ssq[o]);
        ssum[o] += fdpp<DPP_BC31>(ssum[o]);  ssq[o] += fdpp<DPP_BC31>(ssq[o]);
    }
    if (lane == 63) {
        float* baseS = p_sum + ((size_t)(b*64 + cp))*NCH + g*8;
        float* baseQ = p_sqs + ((size_t)(b*64 + cp))*NCH + g*8;
        ((float4*)baseS)[0] = make_float4(sg8[0]*ssum[0], sg8[1]*ssum[1], sg8[2]*ssum[2], sg8[3]*ssum[3]);
        ((float4*)baseS)[1] = make_float4(sg8[4]*ssum[4], sg8[5]*ssum[5], sg8[6]*ssum[6], sg8[7]*ssum[7]);
        ((float4*)baseQ)[0] = make_float4(ssq[0], ssq[1], ssq[2], ssq[3]);
        ((float4*)baseQ)[1] = make_float4(ssq[4], ssq[5], ssq[6], ssq[7]);
    }
}

// K23: fused {channel stats + pool-reduce + BN affine + broadcast write}.
// block = (b, ch). Stats recomputed redundantly per block (8KB L2 reads).
__global__ __launch_bounds__(256) void k23_pool_bcast(
    const float* __restrict__ p_sum, const float* __restrict__ p_sqs,
    const float* __restrict__ p_max,
    const float* __restrict__ gamma, const float* __restrict__ beta,
    fx4* __restrict__ out)
{
    __shared__ float part[16][17];
    __shared__ float wsum[4], wsq[4];
    __shared__ float pool[16];
    const int bc = blockIdx.x;           // b*128 + ch
    const int b  = bc >> 7;
    const int ch = bc & 127;
    const int t  = threadIdx.x;

    // p_max slice reduce (sign-folded maxima)
    const int r = t >> 4, ck = t & 15;
    float v = -FLT_MAX;
    #pragma unroll
    for (int k = 0; k < 4; ++k) {
        const int cpi = ck*4 + k;
        v = fmaxf(v, p_max[(((size_t)(b*64 + cpi))*NRING + r)*NCH + ch]);
    }

    // channel stats: sum this channel's 1024 (b,cp) partials
    float S = 0.f, Q = 0.f;
    #pragma unroll
    for (int i = 0; i < 4; ++i) {
        const int jj = t + i*256;        // [0,1024) = b2*64+cp2
        S += p_sum[(size_t)jj*NCH + ch];
        Q += p_sqs[(size_t)jj*NCH + ch];
    }
    #pragma unroll
    for (int off = 1; off < 64; off <<= 1) {
        S += __shfl_xor(S, off);
        Q += __shfl_xor(Q, off);
    }
    part[r][ck] = v;
    if ((t & 63) == 0) { wsum[t >> 6] = S; wsq[t >> 6] = Q; }
    __syncthreads();

    if (t < 16) {
        const float inv = 1.0f / (float)((size_t)NB * LTOT);
        const float Sa = wsum[0] + wsum[1] + wsum[2] + wsum[3];
        const float Qa = wsq[0] + wsq[1] + wsq[2] + wsq[3];
        const float mean = Sa * inv;
        const float var  = Qa * inv - mean*mean;
        const float istd = rsqrtf(var + 1e-5f);
        float acc = part[t][0];
        #pragma unroll
        for (int k = 1; k < 16; ++k) acc = fmaxf(acc, part[t][k]);
        const float gm = gamma[ch];
        const float raw = (gm >= 0.0f) ? acc : -acc;   // un-fold sign
        pool[t] = gm * (raw - mean) * istd + beta[ch];
    }
    __syncthreads();

    fx4* __restrict__ dst = out + (size_t)bc * (NPT/4);
    #pragma unroll
    for (int i = 0; i < 16; ++i) {
        const int idx = t + i*256;            // [0,4096)
        const float vv = pool[idx >> 8];
        fx4 val; val.x = vv; val.y = vv; val.z = vv; val.w = vv;
        __builtin_nontemporal_store(val, &dst[idx]);
    }
}

extern "C" void kernel_launch(void* const* d_in, const int* in_sizes, int n_in,
                              void* d_out, int out_size, void* d_ws, size_t ws_size,
                              hipStream_t stream)
{
    const float* x     = (const float*)d_in[0];
    const float* Wg    = (const float*)d_in[1];
    const float* bias  = (const float*)d_in[2];
    const float* gamma = (const float*)d_in[3];
    const float* beta  = (const float*)d_in[4];
    const int* choice  = (const int*)d_in[6];

    float* p_sum = (float*)d_ws;                           // 1024*128
    float* p_sqs = p_sum + (size_t)1024*NCH;               // 1024*128
    float* p_max = p_sqs + (size_t)1024*NCH;               // 1024*16*128

    k1_gather_conv<<<NB*CIN*4, 256, 0, stream>>>(x, Wg, bias, gamma, choice,
                                                 p_sum, p_sqs, p_max);
    k23_pool_bcast<<<NB*NCH, 256, 0, stream>>>(p_sum, p_sqs, p_max,
                                               gamma, beta, (fx4*)d_out);
}

// Round 12
// 55.253 us; speedup vs baseline: 1.2980x; 1.1275x over previous
//
#include <hip/hip_runtime.h>
#include <float.h>

#define NB    16
#define CIN   64
#define NPT   16384
#define NRING 16
#define MAXR  1520
#define LTOT  (NRING*MAXR)   // 24320
#define MBLK  380            // LTOT/64
#define NCH   128

typedef float fx4 __attribute__((ext_vector_type(4)));

__device__ __forceinline__ float sload(float v) {
    // force a wave-uniform value into an SGPR
    return __int_as_float(__builtin_amdgcn_readfirstlane(__float_as_int(v)));
}

// DPP move (VALU pipe, zero DS cost)
template<int CTRL>
__device__ __forceinline__ float fdpp(float v) {
    return __int_as_float(__builtin_amdgcn_mov_dpp(__float_as_int(v), CTRL, 0xF, 0xF, true));
}
#define DPP_QP_XOR1 0xB1   // quad_perm [1,0,3,2]
#define DPP_QP_XOR2 0x4E   // quad_perm [2,3,0,1]
#define DPP_SHR1  0x111
#define DPP_SHR2  0x112
#define DPP_SHR4  0x114
#define DPP_SHR8  0x118
#define DPP_BC15  0x142
#define DPP_BC31  0x143

__device__ __forceinline__ void gl_lds16(const float* g, float* l) {
    __builtin_amdgcn_global_load_lds(
        (const __attribute__((address_space(1))) void*)g,
        (__attribute__((address_space(3))) void*)l, 16, 0, 0);
}

// K1 (barrier-free, wave-private double-buffered pipeline, counted vmcnt):
// block = (b, q, cpg) -> 1024 blocks, 4 waves; wave w owns ring g=q*4+w for
// 4 consecutive cp tiles (cp0..cp0+3). LDS: xs[2][4][1024] (32KB dbuf) +
// iw[4][384] (6KB, staged ONCE per block) = 38KB -> 4 blocks/CU resident.
// Phase A: ALL irregular vm loads (choice tails, weights) then vmcnt(0) ->
// exact counting afterwards. Phase B: issue stages s0,s1. Loop tt=0..3:
// vmcnt(4) [s_tt done, next stage still in flight] -> compute -> issue s_tt+2.
// Loop has ZERO vm ops (stores deferred; ssum/ssq accumulated across tiles,
// single DPP reduce at end). choice[p]=p for p<1024 => rows c=0,1 identity.
// Sign-fold: gamma<0 channels use negated weights/bias; only max tracked.
__global__ __launch_bounds__(256) void k1_gather_conv(
    const float* __restrict__ x, const float* __restrict__ Wg,
    const float* __restrict__ bias, const float* __restrict__ gamma,
    const int* __restrict__ choice,
    float* __restrict__ p_sum, float* __restrict__ p_sqs,
    float* __restrict__ p_max)
{
    __shared__ float xs[2][4][1024];   // 32 KB double buffer, wave-private rows
    __shared__ int   iw[4][384];       // 6 KB fused index words, wave-private

    const int blk = blockIdx.x;        // ((b*4+q)<<4) | cpg
    const int cpg = blk & 15;
    const int bq  = blk >> 4;
    const int b   = bq >> 2;
    const int q   = bq & 3;
    const int cp0 = cpg << 2;
    const int t    = threadIdx.x;
    const int w    = t >> 6;
    const int lane = t & 63;
    const int g    = q*4 + w;          // global ring/group index

    // ---- phase A: all irregular vm loads up front ----
    const int* __restrict__ cg = choice + ((size_t)(b*NRING + g))*MAXR;
    const int j1 = lane + 64;
    int4 a0 = *(const int4*)(cg + 760  + 4*lane);
    int4 c0 = *(const int4*)(cg + 1140 + 4*lane);
    int4 a1 = make_int4(0,0,0,0), c1 = make_int4(0,0,0,0);
    if (j1 < 95) {
        a1 = *(const int4*)(cg + 760  + 4*j1);
        c1 = *(const int4*)(cg + 1140 + 4*j1);
    }
    float gv[8], bv[8], w0[8], w1[8], w2[8], w3[8];
    #pragma unroll
    for (int o = 0; o < 8; ++o) {
        const int ch = g*8 + o;
        gv[o] = gamma[ch]; bv[o] = bias[ch];
        w0[o] = Wg[ch*4];  w1[o] = Wg[ch*4+1];
        w2[o] = Wg[ch*4+2]; w3[o] = Wg[ch*4+3];
    }
    // drain ALL vmem so the stage vmcnt counting below is exact
    asm volatile("s_waitcnt vmcnt(0)" ::: "memory");

    // pack + ds_write iw (same-wave DS ordering)
    {
        int4 p;
        p.x = a0.x | (c0.x << 16); p.y = a0.y | (c0.y << 16);
        p.z = a0.z | (c0.z << 16); p.w = a0.w | (c0.w << 16);
        *(int4*)(&iw[w][4*lane]) = p;
        if (j1 < 95) {
            p.x = a1.x | (c1.x << 16); p.y = a1.y | (c1.y << 16);
            p.z = a1.z | (c1.z << 16); p.w = a1.w | (c1.w << 16);
            *(int4*)(&iw[w][4*j1]) = p;
        }
    }
    // wave-uniform weights -> SGPR, sign-folded
    float wq[8][4], bq8[8], sg8[8];
    #pragma unroll
    for (int o = 0; o < 8; ++o) {
        const float sgn = (gv[o] < 0.0f) ? -1.0f : 1.0f;
        sg8[o] = sload(sgn);
        bq8[o] = sload(sgn * bv[o]);
        wq[o][0] = sload(sgn * w0[o]); wq[o][1] = sload(sgn * w1[o]);
        wq[o][2] = sload(sgn * w2[o]); wq[o][3] = sload(sgn * w3[o]);
    }

    #define STAGE(bufi, cpv) do { \
        const float* gb_ = x + ((size_t)(b*CIN + (cpv)))*NPT + (g << 10) + lane*4; \
        float* lb_ = &xs[bufi][w][0]; \
        gl_lds16(gb_,       lb_);       \
        gl_lds16(gb_ + 256, lb_ + 256); \
        gl_lds16(gb_ + 512, lb_ + 512); \
        gl_lds16(gb_ + 768, lb_ + 768); \
    } while (0)

    // ---- phase B: prime the pipeline ----
    STAGE(0, cp0);
    STAGE(1, cp0 + 1);

    const int r = lane >> 2;
    const int s = lane & 3;
    const int* __restrict__ igw = &iw[w][0];

    float smax[4][8], ssum[8], ssq[8];
    #pragma unroll
    for (int o = 0; o < 8; ++o) { ssum[o] = 0.f; ssq[o] = 0.f; }
    #pragma unroll
    for (int tt = 0; tt < 4; ++tt)
        #pragma unroll
        for (int o = 0; o < 8; ++o) smax[tt][o] = -FLT_MAX;

    #pragma unroll
    for (int tt = 0; tt < 4; ++tt) {
        if (tt < 3) { asm volatile("s_waitcnt vmcnt(4)" ::: "memory"); }
        else        { asm volatile("s_waitcnt vmcnt(0)" ::: "memory"); }

        const int cp = cp0 + tt;
        const float* __restrict__ xg = &xs[tt & 1][w][0];
        const int mlo = (r*MAXR - cp + 63) >> 6;
        int mhi = ((r+1)*MAXR - cp + 63) >> 6;
        if (mhi > MBLK) mhi = MBLK;
        const int m0 = mlo + s;

        int wvk[5];
        #pragma unroll
        for (int k = 0; k < 5; ++k) wvk[k] = igw[m0 + 4*k];

        #pragma unroll
        for (int k = 0; k < 5; ++k) {
            const int m  = m0 + 4*k;
            const int i2 = wvk[k] & 0xFFFF;
            const int i3 = ((unsigned)wvk[k]) >> 16;
            const float v0 = xg[m];
            const float v1 = xg[380 + m];
            const float v2 = xg[i2];
            const float v3 = xg[i3];
            #pragma unroll
            for (int o = 0; o < 8; ++o) {
                float y = fmaf(wq[o][0], v0, fmaf(wq[o][1], v1,
                          fmaf(wq[o][2], v2, fmaf(wq[o][3], v3, bq8[o]))));
                smax[tt][o] = fmaxf(smax[tt][o], y);
                ssum[o] += y;
                ssq[o]  = fmaf(y, y, ssq[o]);
            }
        }
        {   // guarded 6th iteration
            const int m = m0 + 20;
            if (m < mhi) {
                const int wt = igw[m];
                const int i2 = wt & 0xFFFF;
                const int i3 = ((unsigned)wt) >> 16;
                const float v0 = xg[m];
                const float v1 = xg[380 + m];
                const float v2 = xg[i2];
                const float v3 = xg[i3];
                #pragma unroll
                for (int o = 0; o < 8; ++o) {
                    float y = fmaf(wq[o][0], v0, fmaf(wq[o][1], v1,
                              fmaf(wq[o][2], v2, fmaf(wq[o][3], v3, bq8[o]))));
                    smax[tt][o] = fmaxf(smax[tt][o], y);
                    ssum[o] += y;
                    ssq[o]  = fmaf(y, y, ssq[o]);
                }
            }
        }

        if (tt < 2) STAGE(tt & 1, cp0 + tt + 2);   // refill the freed buffer
    }
    #undef STAGE

    // ---- deferred reductions + stores (no vm ops inside the loop above) ----
    #pragma unroll
    for (int tt = 0; tt < 4; ++tt) {
        #pragma unroll
        for (int o = 0; o < 8; ++o) {
            smax[tt][o] = fmaxf(smax[tt][o], fdpp<DPP_QP_XOR1>(smax[tt][o]));
            smax[tt][o] = fmaxf(smax[tt][o], fdpp<DPP_QP_XOR2>(smax[tt][o]));
        }
        if (s == 0) {
            float* base = p_max + (((size_t)(b*64 + cp0 + tt))*NRING + r)*NCH + g*8;
            ((float4*)base)[0] = make_float4(smax[tt][0], smax[tt][1], smax[tt][2], smax[tt][3]);
            ((float4*)base)[1] = make_float4(smax[tt][4], smax[tt][5], smax[tt][6], smax[tt][7]);
        }
    }

    // single 6-step DPP wave reduce for the 4-tile channel sums -> lane 63
    #pragma unroll
    for (int o = 0; o < 8; ++o) {
        ssum[o] += fdpp<DPP_SHR1>(ssum[o]);  ssq[o] += fdpp<DPP_SHR1>(ssq[o]);
        ssum[o] += fdpp<DPP_SHR2>(ssum[o]);  ssq[o] += fdpp<DPP_SHR2>(ssq[o]);
        ssum[o] += fdpp<DPP_SHR4>(ssum[o]);  ssq[o] += fdpp<DPP_SHR4>(ssq[o]);
        ssum[o] += fdpp<DPP_SHR8>(ssum[o]);  ssq[o] += fdpp<DPP_SHR8>(ssq[o]);
        ssum[o] += fdpp<DPP_BC15>(ssum[o]);  ssq[o] += fdpp<DPP_BC15>(ssq[o]);
        ssum[o] += fdpp<DPP_BC31>(ssum[o]);  ssq[o] += fdpp<DPP_BC31>(ssq[o]);
    }
    if (lane == 63) {
        float* baseS = p_sum + (size_t)blk*32 + w*8;   // [1024][32] pre-reduced
        float* baseQ = p_sqs + (size_t)blk*32 + w*8;
        ((float4*)baseS)[0] = make_float4(sg8[0]*ssum[0], sg8[1]*ssum[1], sg8[2]*ssum[2], sg8[3]*ssum[3]);
        ((float4*)baseS)[1] = make_float4(sg8[4]*ssum[4], sg8[5]*ssum[5], sg8[6]*ssum[6], sg8[7]*ssum[7]);
        ((float4*)baseQ)[0] = make_float4(ssq[0], ssq[1], ssq[2], ssq[3]);
        ((float4*)baseQ)[1] = make_float4(ssq[4], ssq[5], ssq[6], ssq[7]);
    }
}

// K23: fused {channel stats + pool-reduce + BN affine + broadcast write}.
// block = (b, ch). Stats: 256 pre-reduced partials for this channel (L2).
__global__ __launch_bounds__(256) void k23_pool_bcast(
    const float* __restrict__ p_sum, const float* __restrict__ p_sqs,
    const float* __restrict__ p_max,
    const float* __restrict__ gamma, const float* __restrict__ beta,
    fx4* __restrict__ out)
{
    __shared__ float part[16][17];
    __shared__ float wsum[4], wsq[4];
    __shared__ float pool[16];
    const int bc = blockIdx.x;           // b*128 + ch
    const int b  = bc >> 7;
    const int ch = bc & 127;
    const int t  = threadIdx.x;
    const int q  = ch >> 5, c32 = ch & 31;

    // p_max slice reduce (sign-folded maxima)
    const int r = t >> 4, ck = t & 15;
    float v = -FLT_MAX;
    #pragma unroll
    for (int k = 0; k < 4; ++k) {
        const int cpi = ck*4 + k;
        v = fmaxf(v, p_max[(((size_t)(b*64 + cpi))*NRING + r)*NCH + ch]);
    }

    // channel stats: 256 partials (b2 in [0,16) x cpg in [0,16)) for this ch
    const int b2 = t >> 4, cpg2 = t & 15;
    const int kb = (((b2*4 + q) << 4) | cpg2);
    float S = p_sum[(size_t)kb*32 + c32];
    float Q = p_sqs[(size_t)kb*32 + c32];
    #pragma unroll
    for (int off = 1; off < 64; off <<= 1) {
        S += __shfl_xor(S, off);
        Q += __shfl_xor(Q, off);
    }
    part[r][ck] = v;
    if ((t & 63) == 0) { wsum[t >> 6] = S; wsq[t >> 6] = Q; }
    __syncthreads();

    if (t < 16) {
        const float inv = 1.0f / (float)((size_t)NB * LTOT);
        const float Sa = wsum[0] + wsum[1] + wsum[2] + wsum[3];
        const float Qa = wsq[0] + wsq[1] + wsq[2] + wsq[3];
        const float mean = Sa * inv;
        const float var  = Qa * inv - mean*mean;
        const float istd = rsqrtf(var + 1e-5f);
        float acc = part[t][0];
        #pragma unroll
        for (int k = 1; k < 16; ++k) acc = fmaxf(acc, part[t][k]);
        const float gm = gamma[ch];
        const float raw = (gm >= 0.0f) ? acc : -acc;   // un-fold sign
        pool[t] = gm * (raw - mean) * istd + beta[ch];
    }
    __syncthreads();

    fx4* __restrict__ dst = out + (size_t)bc * (NPT/4);
    #pragma unroll
    for (int i = 0; i < 16; ++i) {
        const int idx = t + i*256;            // [0,4096)
        const float vv = pool[idx >> 8];
        fx4 val; val.x = vv; val.y = vv; val.z = vv; val.w = vv;
        __builtin_nontemporal_store(val, &dst[idx]);
    }
}

extern "C" void kernel_launch(void* const* d_in, const int* in_sizes, int n_in,
                              void* d_out, int out_size, void* d_ws, size_t ws_size,
                              hipStream_t stream)
{
    const float* x     = (const float*)d_in[0];
    const float* Wg    = (const float*)d_in[1];
    const float* bias  = (const float*)d_in[2];
    const float* gamma = (const float*)d_in[3];
    const float* beta  = (const float*)d_in[4];
    const int* choice  = (const int*)d_in[6];

    float* p_sum = (float*)d_ws;                           // 1024*32
    float* p_sqs = p_sum + (size_t)1024*32;                // 1024*32
    float* p_max = p_sqs + (size_t)1024*32;                // 1024*16*128

    k1_gather_conv<<<1024, 256, 0, stream>>>(x, Wg, bias, gamma, choice,
                                             p_sum, p_sqs, p_max);
    k23_pool_bcast<<<NB*NCH, 256, 0, stream>>>(p_sum, p_sqs, p_max,
                                               gamma, beta, (fx4*)d_out);
}

// Round 14
// 54.276 us; speedup vs baseline: 1.3213x; 1.0180x over previous
//
#include <hip/hip_runtime.h>
#include <hip/hip_fp16.h>
#include <float.h>

#define NB    16
#define CIN   64
#define NPT   16384
#define NRING 16
#define MAXR  1520
#define LTOT  (NRING*MAXR)   // 24320
#define MBLK  380            // LTOT/64
#define NCH   128

typedef float fx4 __attribute__((ext_vector_type(4)));

static __device__ __forceinline__ float sload(float v) {
    return __int_as_float(__builtin_amdgcn_readfirstlane(__float_as_int(v)));
}
static __device__ __forceinline__ unsigned h2u(__half2 h) {
    union { __half2 h; unsigned u; } c; c.h = h; return c.u;
}
static __device__ __forceinline__ __half2 u2h(unsigned u) {
    union { unsigned u; __half2 h; } c; c.u = u; return c.h;
}
static __device__ __forceinline__ __half2 hload(__half2 v) {  // wave-uniform -> SGPR
    return u2h((unsigned)__builtin_amdgcn_readfirstlane((int)h2u(v)));
}
// packed f16 max (no __hmax2 in ROCm HIP headers): single v_pk_max_f16
static __device__ __forceinline__ __half2 pkmax(__half2 a, __half2 b) {
    unsigned d, ua = h2u(a), ub = h2u(b);
    asm("v_pk_max_f16 %0, %1, %2" : "=v"(d) : "v"(ua), "v"(ub));
    return u2h(d);
}

template<int CTRL>
static __device__ __forceinline__ float fdpp(float v) {
    return __int_as_float(__builtin_amdgcn_mov_dpp(__float_as_int(v), CTRL, 0xF, 0xF, true));
}
template<int CTRL>
static __device__ __forceinline__ __half2 hdpp(__half2 v) {
    return u2h((unsigned)__builtin_amdgcn_mov_dpp((int)h2u(v), CTRL, 0xF, 0xF, true));
}
#define DPP_QP_XOR1 0xB1   // quad_perm [1,0,3,2]
#define DPP_QP_XOR2 0x4E   // quad_perm [2,3,0,1]
#define DPP_SHR1  0x111
#define DPP_SHR2  0x112
#define DPP_SHR4  0x114
#define DPP_SHR8  0x118
#define DPP_BC15  0x142
#define DPP_BC31  0x143

// K1 (barrier-free, fp16x2 cp-pair packing): block = (b, q, pg) -> 1024 blocks,
// 4 waves; wave w owns ring g=q*4+w. Block covers cp0..cp0+3 as TWO pk tiles:
// tile tt = cp pair (cp0+2tt, cp0+2tt+1). LDS word i of a tile = half2(x[cpe][i],
// x[cpo][i]) -> one ds_read serves 2 outputs; v_pk_fma computes 2 cp at once.
// KEY: m-window boundary-change cp values are 48r+63 / 48r+47 (mod 64) - always
// ODD - so (even,odd) pairs share identical m-windows: pk loop is exact, no mask.
// Stats: fp16 pk accum per tile (<=6 terms), flushed to f32 -> error ~1e-3 << thr.
// Stage: reg-load + cvt pack + ds_write; tile1 loads issued before tile0
// compute (latency hides); wave-private LDS -> zero barriers. DPP reductions.
// Sign-fold: gamma<0 channels use negated weights/bias; only max tracked.
__global__ __launch_bounds__(256) void k1_gather_conv(
    const float* __restrict__ x, const float* __restrict__ Wg,
    const float* __restrict__ bias, const float* __restrict__ gamma,
    const int* __restrict__ choice,
    float* __restrict__ p_sum, float* __restrict__ p_sqs,
    float* __restrict__ p_max)
{
    __shared__ unsigned xs[2][4][1024];   // 32 KB: half2-packed cp-pair rows
    __shared__ int iw[4][384];            // 6 KB fused index words, wave-private

    const int blk = blockIdx.x;           // ((b*4+q)<<4) | pg
    const int pg  = blk & 15;
    const int bq  = blk >> 4;
    const int b   = bq >> 2;
    const int q   = bq & 3;
    const int cp0 = pg << 2;
    const int t    = threadIdx.x;
    const int w    = t >> 6;
    const int lane = t & 63;
    const int g    = q*4 + w;             // global ring/group index
    const int r    = lane >> 2;
    const int s    = lane & 3;

    // ---- issue tile0 pair-row loads (cp0, cp0+1) ----
    const float* rb = x + ((size_t)(b*CIN + cp0))*NPT + (g << 10) + 4*lane;
    fx4 e0[4], f0[4];
    #pragma unroll
    for (int k = 0; k < 4; ++k) {
        e0[k] = *(const fx4*)(rb + 256*k);
        f0[k] = *(const fx4*)(rb + NPT + 256*k);
    }

    // ---- choice tail loads (coalesced int4) ----
    const int* __restrict__ cg = choice + ((size_t)(b*NRING + g))*MAXR;
    const int j1 = lane + 64;
    int4 a0 = *(const int4*)(cg + 760  + 4*lane);
    int4 c0 = *(const int4*)(cg + 1140 + 4*lane);
    int4 a1 = make_int4(0,0,0,0), c1 = make_int4(0,0,0,0);
    if (j1 < 95) {
        a1 = *(const int4*)(cg + 760  + 4*j1);
        c1 = *(const int4*)(cg + 1140 + 4*j1);
    }

    // ---- weight raw loads ----
    float gv[8], bv[8], wraw[8][4];
    #pragma unroll
    for (int o = 0; o < 8; ++o) {
        const int ch = g*8 + o;
        gv[o] = gamma[ch]; bv[o] = bias[ch];
        #pragma unroll
        for (int c = 0; c < 4; ++c) wraw[o][c] = Wg[ch*4 + c];
    }

    // ---- write iw (same-wave DS ordering) ----
    {
        int4 p;
        p.x = a0.x | (c0.x << 16); p.y = a0.y | (c0.y << 16);
        p.z = a0.z | (c0.z << 16); p.w = a0.w | (c0.w << 16);
        *(int4*)(&iw[w][4*lane]) = p;
        if (j1 < 95) {
            p.x = a1.x | (c1.x << 16); p.y = a1.y | (c1.y << 16);
            p.z = a1.z | (c1.z << 16); p.w = a1.w | (c1.w << 16);
            *(int4*)(&iw[w][4*j1]) = p;
        }
    }

    // ---- pack + write xs0 ----
    #pragma unroll
    for (int k = 0; k < 4; ++k) {
        uint4 u;
        u.x = h2u(__float22half2_rn(make_float2(e0[k].x, f0[k].x)));
        u.y = h2u(__float22half2_rn(make_float2(e0[k].y, f0[k].y)));
        u.z = h2u(__float22half2_rn(make_float2(e0[k].z, f0[k].z)));
        u.w = h2u(__float22half2_rn(make_float2(e0[k].w, f0[k].w)));
        *(uint4*)&xs[0][w][4*lane + 256*k] = u;
    }

    // ---- sign-folded pk weights -> SGPR ----
    __half2 wp[8][4], bp[8];
    float sg8[8];
    #pragma unroll
    for (int o = 0; o < 8; ++o) {
        const float sgn = (gv[o] < 0.0f) ? -1.0f : 1.0f;
        sg8[o] = sload(sgn);
        bp[o]  = hload(__half2half2(__float2half(sgn * bv[o])));
        #pragma unroll
        for (int c = 0; c < 4; ++c)
            wp[o][c] = hload(__half2half2(__float2half(sgn * wraw[o][c])));
    }

    // ---- issue tile1 pair-row loads (cp0+2, cp0+3); hide under tile0 compute ----
    fx4 e1[4], f1[4];
    #pragma unroll
    for (int k = 0; k < 4; ++k) {
        e1[k] = *(const fx4*)(rb + 2*NPT + 256*k);
        f1[k] = *(const fx4*)(rb + 3*NPT + 256*k);
    }
    asm volatile("" ::: "memory");   // keep the loads issued here

    const int* __restrict__ igw = &iw[w][0];
    float ssum[8], ssq[8];
    #pragma unroll
    for (int o = 0; o < 8; ++o) { ssum[o] = 0.f; ssq[o] = 0.f; }

    auto TILE = [&](int cpe, const unsigned* __restrict__ xg) {
        const int mlo = (r*MAXR - cpe + 63) >> 6;       // identical for cpe, cpe+1
        const int mhi = ((r+1)*MAXR - cpe + 63) >> 6;   // <= 380 always
        const int m0  = mlo + s;

        int wvk[5];
        #pragma unroll
        for (int k = 0; k < 5; ++k) wvk[k] = igw[m0 + 4*k];

        __half2 hmax[8], hsum[8], hsq[8];
        #pragma unroll
        for (int o = 0; o < 8; ++o) {
            hmax[o] = u2h(0xFC00FC00u);  // pk -inf
            hsum[o] = u2h(0u); hsq[o] = u2h(0u);
        }

        #pragma unroll
        for (int k = 0; k < 5; ++k) {
            const int m  = m0 + 4*k;
            const int i2 = wvk[k] & 0xFFFF;
            const int i3 = ((unsigned)wvk[k]) >> 16;
            const __half2 v0 = u2h(xg[m]);           // c=0: identity
            const __half2 v1 = u2h(xg[380 + m]);     // c=1: identity
            const __half2 v2 = u2h(xg[i2]);          // c=2
            const __half2 v3 = u2h(xg[i3]);          // c=3
            #pragma unroll
            for (int o = 0; o < 8; ++o) {
                __half2 y = __hfma2(wp[o][0], v0, __hfma2(wp[o][1], v1,
                            __hfma2(wp[o][2], v2, __hfma2(wp[o][3], v3, bp[o]))));
                hmax[o] = pkmax(hmax[o], y);
                hsum[o] = __hadd2(hsum[o], y);
                hsq[o]  = __hfma2(y, y, hsq[o]);
            }
        }
        {   // guarded 6th iteration
            const int m = m0 + 20;
            if (m < mhi) {
                const int wt = igw[m];
                const int i2 = wt & 0xFFFF;
                const int i3 = ((unsigned)wt) >> 16;
                const __half2 v0 = u2h(xg[m]);
                const __half2 v1 = u2h(xg[380 + m]);
                const __half2 v2 = u2h(xg[i2]);
                const __half2 v3 = u2h(xg[i3]);
                #pragma unroll
                for (int o = 0; o < 8; ++o) {
                    __half2 y = __hfma2(wp[o][0], v0, __hfma2(wp[o][1], v1,
                                __hfma2(wp[o][2], v2, __hfma2(wp[o][3], v3, bp[o]))));
                    hmax[o] = pkmax(hmax[o], y);
                    hsum[o] = __hadd2(hsum[o], y);
                    hsq[o]  = __hfma2(y, y, hsq[o]);
                }
            }
        }

        // flush tile stats to f32 (both halves are distinct cp's of same channel)
        #pragma unroll
        for (int o = 0; o < 8; ++o) {
            ssum[o] += __low2float(hsum[o]) + __high2float(hsum[o]);
            ssq[o]  += __low2float(hsq[o])  + __high2float(hsq[o]);
        }
        // quad-combine the 4 s-copies (VALU DPP) + store both cp rows
        #pragma unroll
        for (int o = 0; o < 8; ++o) {
            hmax[o] = pkmax(hmax[o], hdpp<DPP_QP_XOR1>(hmax[o]));
            hmax[o] = pkmax(hmax[o], hdpp<DPP_QP_XOR2>(hmax[o]));
        }
        if (s == 0) {
            float* be = p_max + (((size_t)(b*64 + cpe))*NRING + r)*NCH + g*8;
            float* bo = be + (size_t)NRING*NCH;   // cp+1 row
            ((float4*)be)[0] = make_float4(__low2float(hmax[0]), __low2float(hmax[1]),
                                           __low2float(hmax[2]), __low2float(hmax[3]));
            ((float4*)be)[1] = make_float4(__low2float(hmax[4]), __low2float(hmax[5]),
                                           __low2float(hmax[6]), __low2float(hmax[7]));
            ((float4*)bo)[0] = make_float4(__high2float(hmax[0]), __high2float(hmax[1]),
                                           __high2float(hmax[2]), __high2float(hmax[3]));
            ((float4*)bo)[1] = make_float4(__high2float(hmax[4]), __high2float(hmax[5]),
                                           __high2float(hmax[6]), __high2float(hmax[7]));
        }
    };

    TILE(cp0, &xs[0][w][0]);

    // pack + write xs1 (loads already in flight since before tile0)
    #pragma unroll
    for (int k = 0; k < 4; ++k) {
        uint4 u;
        u.x = h2u(__float22half2_rn(make_float2(e1[k].x, f1[k].x)));
        u.y = h2u(__float22half2_rn(make_float2(e1[k].y, f1[k].y)));
        u.z = h2u(__float22half2_rn(make_float2(e1[k].z, f1[k].z)));
        u.w = h2u(__float22half2_rn(make_float2(e1[k].w, f1[k].w)));
        *(uint4*)&xs[1][w][4*lane + 256*k] = u;
    }

    TILE(cp0 + 2, &xs[1][w][0]);

    // ---- single 6-step DPP f32 wave reduce for channel sums -> lane 63 ----
    #pragma unroll
    for (int o = 0; o < 8; ++o) {
        ssum[o] += fdpp<DPP_SHR1>(ssum[o]);  ssq[o] += fdpp<DPP_SHR1>(ssq[o]);
        ssum[o] += fdpp<DPP_SHR2>(ssum[o]);  ssq[o] += fdpp<DPP_SHR2>(ssq[o]);
        ssum[o] += fdpp<DPP_SHR4>(ssum[o]);  ssq[o] += fdpp<DPP_SHR4>(ssq[o]);
        ssum[o] += fdpp<DPP_SHR8>(ssum[o]);  ssq[o] += fdpp<DPP_SHR8>(ssq[o]);
        ssum[o] += fdpp<DPP_BC15>(ssum[o]);  ssq[o] += fdpp<DPP_BC15>(ssq[o]);
        ssum[o] += fdpp<DPP_BC31>(ssum[o]);  ssq[o] += fdpp<DPP_BC31>(ssq[o]);
    }
    if (lane == 63) {
        float* baseS = p_sum + (size_t)blk*32 + w*8;   // [1024][32] pre-reduced
        float* baseQ = p_sqs + (size_t)blk*32 + w*8;
        ((float4*)baseS)[0] = make_float4(sg8[0]*ssum[0], sg8[1]*ssum[1], sg8[2]*ssum[2], sg8[3]*ssum[3]);
        ((float4*)baseS)[1] = make_float4(sg8[4]*ssum[4], sg8[5]*ssum[5], sg8[6]*ssum[6], sg8[7]*ssum[7]);
        ((float4*)baseQ)[0] = make_float4(ssq[0], ssq[1], ssq[2], ssq[3]);
        ((float4*)baseQ)[1] = make_float4(ssq[4], ssq[5], ssq[6], ssq[7]);
    }
}

// K23: fused {channel stats + pool-reduce + BN affine + broadcast write}.
// block = (b, ch). Stats: 256 pre-reduced partials for this channel (L2).
__global__ __launch_bounds__(256) void k23_pool_bcast(
    const float* __restrict__ p_sum, const float* __restrict__ p_sqs,
    const float* __restrict__ p_max,
    const float* __restrict__ gamma, const float* __restrict__ beta,
    fx4* __restrict__ out)
{
    __shared__ float part[16][17];
    __shared__ float wsum[4], wsq[4];
    __shared__ float pool[16];
    const int bc = blockIdx.x;           // b*128 + ch
    const int b  = bc >> 7;
    const int ch = bc & 127;
    const int t  = threadIdx.x;
    const int q  = ch >> 5, c32 = ch & 31;

    // p_max slice reduce (sign-folded maxima)
    const int r = t >> 4, ck = t & 15;
    float v = -FLT_MAX;
    #pragma unroll
    for (int k = 0; k < 4; ++k) {
        const int cpi = ck*4 + k;
        v = fmaxf(v, p_max[(((size_t)(b*64 + cpi))*NRING + r)*NCH + ch]);
    }

    // channel stats: 256 partials (b2 in [0,16) x pg in [0,16)) for this ch
    const int b2 = t >> 4, pg2 = t & 15;
    const int kb = (((b2*4 + q) << 4) | pg2);
    float S = p_sum[(size_t)kb*32 + c32];
    float Q = p_sqs[(size_t)kb*32 + c32];
    #pragma unroll
    for (int off = 1; off < 64; off <<= 1) {
        S += __shfl_xor(S, off);
        Q += __shfl_xor(Q, off);
    }
    part[r][ck] = v;
    if ((t & 63) == 0) { wsum[t >> 6] = S; wsq[t >> 6] = Q; }
    __syncthreads();

    if (t < 16) {
        const float inv = 1.0f / (float)((size_t)NB * LTOT);
        const float Sa = wsum[0] + wsum[1] + wsum[2] + wsum[3];
        const float Qa = wsq[0] + wsq[1] + wsq[2] + wsq[3];
        const float mean = Sa * inv;
        const float var  = Qa * inv - mean*mean;
        const float istd = rsqrtf(var + 1e-5f);
        float acc = part[t][0];
        #pragma unroll
        for (int k = 1; k < 16; ++k) acc = fmaxf(acc, part[t][k]);
        const float gm = gamma[ch];
        const float raw = (gm >= 0.0f) ? acc : -acc;   // un-fold sign
        pool[t] = gm * (raw - mean) * istd + beta[ch];
    }
    __syncthreads();

    fx4* __restrict__ dst = out + (size_t)bc * (NPT/4);
    #pragma unroll
    for (int i = 0; i < 16; ++i) {
        const int idx = t + i*256;            // [0,4096)
        const float vv = pool[idx >> 8];
        fx4 val; val.x = vv; val.y = vv; val.z = vv; val.w = vv;
        __builtin_nontemporal_store(val, &dst[idx]);
    }
}

extern "C" void kernel_launch(void* const* d_in, const int* in_sizes, int n_in,
                              void* d_out, int out_size, void* d_ws, size_t ws_size,
                              hipStream_t stream)
{
    const float* x     = (const float*)d_in[0];
    const float* Wg    = (const float*)d_in[1];
    const float* bias  = (const float*)d_in[2];
    const float* gamma = (const float*)d_in[3];
    const float* beta  = (const float*)d_in[4];
    const int* choice  = (const int*)d_in[6];

    float* p_sum = (float*)d_ws;                           // 1024*32
    float* p_sqs = p_sum + (size_t)1024*32;                // 1024*32
    float* p_max = p_sqs + (size_t)1024*32;                // 1024*16*128

    k1_gather_conv<<<1024, 256, 0, stream>>>(x, Wg, bias, gamma, choice,
                                             p_sum, p_sqs, p_max);
    k23_pool_bcast<<<NB*NCH, 256, 0, stream>>>(p_sum, p_sqs, p_max,
                                               gamma, beta, (fx4*)d_out);
}